// Round 1
// baseline (957.215 us; speedup 1.0000x reference)
//
#include <hip/hip_runtime.h>
#include <hip/hip_bf16.h>

#define BN 2
#define SEQ 2048
#define DM 1024
#define NH 16
#define DK 64

using f32x4  = __attribute__((ext_vector_type(4))) float;
using bf16x8 = __attribute__((ext_vector_type(8))) __bf16;
using short8 = __attribute__((ext_vector_type(8))) short;

static_assert(sizeof(bf16x8) == 16, "bf16x8 must be 16B");

__device__ __forceinline__ unsigned short f2b(float f) {
    __hip_bfloat16 h = __float2bfloat16(f);
    return __builtin_bit_cast(unsigned short, h);
}

__device__ __forceinline__ bf16x8 load_bf8(const unsigned short* p) {
    short8 s = *reinterpret_cast<const short8*>(p);
    return __builtin_bit_cast(bf16x8, s);
}

// ---------------------------------------------------------------- bias table
// bias_val[h][d+2047] for d in [-2047,2047], exact integer bucket thresholds.
__global__ void bias_table_kernel(const float* __restrict__ rel,
                                  float* __restrict__ bias_val) {
    int idx = blockIdx.x * 256 + threadIdx.x;
    if (idx >= NH * 4095) return;
    int h = idx / 4095;
    int dd = idx - h * 4095;
    int d = dd - 2047;
    int a = d < 0 ? -d : d;
    int bucket;
    if (a == 0) bucket = 0;
    else if (a < 8) bucket = 16 + a;
    else {
        int k = (a >= 14) + (a >= 23) + (a >= 39) + (a >= 64) +
                (a >= 108) + (a >= 182) + (a >= 305);
        bucket = 24 + k;                     // 16 + min(15, 8+k), k<=7
    }
    bias_val[h * 4095 + dd] = rel[bucket * NH + h];
}

// ---------------------------------------------------------------- projections
// C[M=4096, N=1024] = A[4096,1024] @ W[1024,1024] (+bias)*outscale
// AMODE 0: A fp32   AMODE 1: A bf16
// OMODE 0: bf16 natural; OMODE 1: bf16 transposed per-head [b][h][d][s]; OMODE 2: fp32
template<int AMODE, int OMODE>
__global__ __launch_bounds__(256) void proj_gemm(const void* __restrict__ Ain,
        const float* __restrict__ W, const float* __restrict__ bias,
        void* __restrict__ Out, float outscale) {
    constexpr int KP = 40;                   // LDS pitch (bf16 elems), 80B rows
    __shared__ unsigned short la[128 * KP];
    __shared__ unsigned short lb[128 * KP];  // stores W transposed: lb[n][k]
    const int tid = threadIdx.x;
    const int bx = blockIdx.x & 7, by = blockIdx.x >> 3;
    const int m0 = by * 128, n0 = bx * 128;
    const int lane = tid & 63, wid = tid >> 6;
    const int wm0 = (wid >> 1) * 64, wn0 = (wid & 1) * 64;
    const int l15 = lane & 15, l4 = lane >> 4;
    f32x4 acc[4][4] = {};

    for (int kt = 0; kt < 32; ++kt) {
        const int k0 = kt * 32;
        // stage A tile [128][32] -> la
        if (AMODE == 0) {
            const float* A = (const float*)Ain;
#pragma unroll
            for (int i = 0; i < 4; ++i) {
                int idx = tid + i * 256;
                int row = idx >> 3, c4 = (idx & 7) * 4;
                float4 v = *(const float4*)(A + (size_t)(m0 + row) * DM + k0 + c4);
                ushort4 u; u.x = f2b(v.x); u.y = f2b(v.y); u.z = f2b(v.z); u.w = f2b(v.w);
                *(ushort4*)&la[row * KP + c4] = u;
            }
        } else {
            const unsigned short* A = (const unsigned short*)Ain;
#pragma unroll
            for (int i = 0; i < 2; ++i) {
                int idx = tid + i * 256;
                int row = idx >> 2, c8 = (idx & 3) * 8;
                int4 v = *(const int4*)(A + (size_t)(m0 + row) * DM + k0 + c8);
                *(int4*)&la[row * KP + c8] = v;
            }
        }
        // stage B tile: W[k0..k0+31][n0..n0+127] transposed -> lb[n][k]
#pragma unroll
        for (int i = 0; i < 4; ++i) {
            int idx = tid + i * 256;
            int n = idx & 127, k4 = (idx >> 7) * 4;
            const float* wp = W + (size_t)(k0 + k4) * DM + n0 + n;
            ushort4 u;
            u.x = f2b(wp[0 * DM]); u.y = f2b(wp[1 * DM]);
            u.z = f2b(wp[2 * DM]); u.w = f2b(wp[3 * DM]);
            *(ushort4*)&lb[n * KP + k4] = u;
        }
        __syncthreads();
        bf16x8 af[4], bfv[4];
#pragma unroll
        for (int m = 0; m < 4; ++m)
            af[m] = load_bf8(&la[(wm0 + m * 16 + l15) * KP + l4 * 8]);
#pragma unroll
        for (int n = 0; n < 4; ++n)
            bfv[n] = load_bf8(&lb[(wn0 + n * 16 + l15) * KP + l4 * 8]);
#pragma unroll
        for (int m = 0; m < 4; ++m)
#pragma unroll
            for (int n = 0; n < 4; ++n)
                acc[m][n] = __builtin_amdgcn_mfma_f32_16x16x32_bf16(af[m], bfv[n], acc[m][n], 0, 0, 0);
        __syncthreads();
    }

    float bv[4];
#pragma unroll
    for (int n = 0; n < 4; ++n) bv[n] = bias[n0 + wn0 + n * 16 + l15];
#pragma unroll
    for (int m = 0; m < 4; ++m) {
#pragma unroll
        for (int n = 0; n < 4; ++n) {
            int gcol = n0 + wn0 + n * 16 + l15;
#pragma unroll
            for (int r = 0; r < 4; ++r) {
                int grow = m0 + wm0 + m * 16 + l4 * 4 + r;
                float val = (acc[m][n][r] + bv[n]) * outscale;
                if (OMODE == 0) {
                    ((unsigned short*)Out)[(size_t)grow * DM + gcol] = f2b(val);
                } else if (OMODE == 1) {
                    int b = grow >> 11, s = grow & 2047;
                    int hh = gcol >> 6, dl = gcol & 63;
                    ((unsigned short*)Out)[(((size_t)(b * NH + hh) * DK + dl) << 11) + s] = f2b(val);
                } else {
                    ((float*)Out)[(size_t)grow * DM + gcol] = val;
                }
            }
        }
    }
}

// ---------------------------------------------------------------- attention
// One block = (b, h, 16 query rows). Scores tile 16x2048 fp32 in LDS.
__global__ __launch_bounds__(256) void attn_kernel(
        const unsigned short* __restrict__ Qp, const unsigned short* __restrict__ Kp,
        const unsigned short* __restrict__ Vt, const float* __restrict__ bias_val,
        float* __restrict__ attn_out, unsigned short* __restrict__ ctx) {
    constexpr int SP = 2052;                 // padded pitch (floats)
    __shared__ float sc[16 * SP];
    __shared__ float rmax[16];
    __shared__ float rscale[16];
    const int tid = threadIdx.x;
    const int lane = tid & 63, wid = tid >> 6;
    const int l15 = lane & 15, l4 = lane >> 4;
    const int bid = blockIdx.x;
    const int qt = bid & 127;
    const int h = (bid >> 7) & 15;
    const int b = bid >> 11;
    const int q0 = qt * 16;

    // Q fragments (scaled by 1/8 already)
    const unsigned short* qbase = Qp + (size_t)(b * SEQ + q0 + l15) * DM + h * DK;
    bf16x8 qa0 = load_bf8(qbase + l4 * 8);
    bf16x8 qa1 = load_bf8(qbase + 32 + l4 * 8);

    // phase 1: scores = Q K^T  (each wave owns 512 key columns)
    const unsigned short* kbase = Kp + (size_t)b * SEQ * DM + h * DK;
    for (int ct = 0; ct < 32; ++ct) {
        int j0 = wid * 512 + ct * 16;
        const unsigned short* kp = kbase + (size_t)(j0 + l15) * DM;
        bf16x8 kb0 = load_bf8(kp + l4 * 8);
        bf16x8 kb1 = load_bf8(kp + 32 + l4 * 8);
        f32x4 a = {};
        a = __builtin_amdgcn_mfma_f32_16x16x32_bf16(qa0, kb0, a, 0, 0, 0);
        a = __builtin_amdgcn_mfma_f32_16x16x32_bf16(qa1, kb1, a, 0, 0, 0);
#pragma unroll
        for (int r = 0; r < 4; ++r)
            sc[(l4 * 4 + r) * SP + j0 + l15] = a[r];
    }
    __syncthreads();

    // phase 2: add bias, row max (16 threads per row)
    const int rr = tid >> 4, st = tid & 15;
    const float* brow = bias_val + h * 4095 + (2047 - (q0 + rr));
    float mx = -1e30f;
    for (int c = st; c < SEQ; c += 16) {
        float s = sc[rr * SP + c] + brow[c];
        sc[rr * SP + c] = s;
        mx = fmaxf(mx, s);
    }
#pragma unroll
    for (int off = 1; off < 16; off <<= 1) mx = fmaxf(mx, __shfl_xor(mx, off));
    if (st == 0) rmax[rr] = mx;
    __syncthreads();

    // phase 3: exp + row sum
    const float rm = rmax[rr];
    float sum = 0.f;
    for (int c = st; c < SEQ; c += 16) {
        float e = __expf(sc[rr * SP + c] - rm);
        sc[rr * SP + c] = e;
        sum += e;
    }
#pragma unroll
    for (int off = 1; off < 16; off <<= 1) sum += __shfl_xor(sum, off);
    if (st == 0) rscale[rr] = 1.0f / sum;
    __syncthreads();

    // phase 4a: write normalized attention weights (float4, coalesced)
    float* abase = attn_out + ((size_t)((b * NH + h) * SEQ + q0)) * SEQ;
#pragma unroll 4
    for (int i = 0; i < 32; ++i) {
        int fi = (i * 256 + tid) * 4;
        int r = fi >> 11, c = fi & 2047;
        float4 e4 = *(const float4*)&sc[r * SP + c];
        float scl = rscale[r];
        float4 o; o.x = e4.x * scl; o.y = e4.y * scl; o.z = e4.z * scl; o.w = e4.w * scl;
        *(float4*)(abase + (size_t)r * SEQ + c) = o;
    }

    // phase 4b: context = P V  (each wave owns 16 of the 64 head dims)
    const unsigned short* vb = Vt + (((size_t)(b * NH + h) * DK + wid * 16 + l15) << 11);
    f32x4 pv = {};
    for (int kt = 0; kt < 64; ++kt) {
        const float* sp = &sc[l15 * SP + kt * 32 + l4 * 8];
        float4 w0 = *(const float4*)sp;
        float4 w1 = *(const float4*)(sp + 4);
        short8 aws;
        aws[0] = (short)f2b(w0.x); aws[1] = (short)f2b(w0.y);
        aws[2] = (short)f2b(w0.z); aws[3] = (short)f2b(w0.w);
        aws[4] = (short)f2b(w1.x); aws[5] = (short)f2b(w1.y);
        aws[6] = (short)f2b(w1.z); aws[7] = (short)f2b(w1.w);
        bf16x8 aw = __builtin_bit_cast(bf16x8, aws);
        bf16x8 vv = load_bf8(vb + kt * 32 + l4 * 8);
        pv = __builtin_amdgcn_mfma_f32_16x16x32_bf16(aw, vv, pv, 0, 0, 0);
    }
#pragma unroll
    for (int r = 0; r < 4; ++r) {
        int row = l4 * 4 + r;
        float val = pv[r] * rscale[row];
        ctx[(size_t)(b * SEQ + q0 + row) * DM + h * DK + wid * 16 + l15] = f2b(val);
    }
}

// ---------------------------------------------------------------- pb writer
__global__ __launch_bounds__(256) void pb_kernel(const float* __restrict__ bias_val,
                                                 float* __restrict__ pb) {
    unsigned int t4 = blockIdx.x * 256u + threadIdx.x;
    int j = (t4 & 511) * 4;
    int i = (t4 >> 9) & 2047;
    int h = t4 >> 20;
    const float* bp = bias_val + h * 4095 + (j - i + 2047);
    float4 v; v.x = bp[0]; v.y = bp[1]; v.z = bp[2]; v.w = bp[3];
    size_t off = ((size_t)(h * SEQ + i) << 11) + j;
    *(float4*)(pb + off) = v;
    *(float4*)(pb + off + (size_t)NH * SEQ * SEQ) = v;
}

// ---------------------------------------------------------------- launcher
extern "C" void kernel_launch(void* const* d_in, const int* in_sizes, int n_in,
                              void* d_out, int out_size, void* d_ws, size_t ws_size,
                              hipStream_t stream) {
    const float* query = (const float*)d_in[0];
    const float* key   = (const float*)d_in[1];
    const float* value = (const float*)d_in[2];
    const float* Wq = (const float*)d_in[3];
    const float* bq = (const float*)d_in[4];
    const float* Wk = (const float*)d_in[5];
    const float* bk = (const float*)d_in[6];
    const float* Wv = (const float*)d_in[7];
    const float* bv = (const float*)d_in[8];
    const float* Wo = (const float*)d_in[9];
    const float* bo = (const float*)d_in[10];
    const float* rel = (const float*)d_in[11];

    float* out = (float*)d_out;
    float* attn_out = out + (size_t)BN * SEQ * DM;                 // 4,194,304
    float* pb_out = attn_out + (size_t)BN * NH * SEQ * SEQ;        // +134,217,728

    char* ws = (char*)d_ws;
    float* bias_val = (float*)ws;                                  // 256KB slot
    unsigned short* Qp = (unsigned short*)(ws + 262144);
    unsigned short* Kp = Qp + (size_t)BN * SEQ * DM;
    unsigned short* Vt = Kp + (size_t)BN * SEQ * DM;
    unsigned short* ctx = Vt + (size_t)BN * SEQ * DM;

    bias_table_kernel<<<256, 256, 0, stream>>>(rel, bias_val);
    proj_gemm<0, 0><<<256, 256, 0, stream>>>(query, Wq, bq, Qp, 0.125f);
    proj_gemm<0, 0><<<256, 256, 0, stream>>>(key, Wk, bk, Kp, 1.0f);
    proj_gemm<0, 1><<<256, 256, 0, stream>>>(value, Wv, bv, Vt, 1.0f);
    attn_kernel<<<BN * NH * (SEQ / 16), 256, 0, stream>>>(Qp, Kp, Vt, bias_val, attn_out, ctx);
    proj_gemm<1, 2><<<256, 256, 0, stream>>>(ctx, Wo, bo, out, 1.0f);
    pb_kernel<<<65536, 256, 0, stream>>>(bias_val, pb_out);
}

// Round 2
// 709.989 us; speedup vs baseline: 1.3482x; 1.3482x over previous
//
#include <hip/hip_runtime.h>
#include <hip/hip_bf16.h>

#define BN 2
#define SEQ 2048
#define DM 1024
#define NH 16
#define DK 64

using f32x4  = __attribute__((ext_vector_type(4))) float;
using bf16x8 = __attribute__((ext_vector_type(8))) __bf16;
using short8 = __attribute__((ext_vector_type(8))) short;

static_assert(sizeof(bf16x8) == 16, "bf16x8 must be 16B");

#define MFMA16(a, b, c) __builtin_amdgcn_mfma_f32_16x16x32_bf16(a, b, c, 0, 0, 0)

__device__ __forceinline__ unsigned short f2b(float f) {
    __hip_bfloat16 h = __float2bfloat16(f);
    return __builtin_bit_cast(unsigned short, h);
}

__device__ __forceinline__ bf16x8 load_bf8(const unsigned short* p) {
    short8 s = *reinterpret_cast<const short8*>(p);
    return __builtin_bit_cast(bf16x8, s);
}

// ---------------------------------------------------------------- bias table
// bias_val[h][d+2047] for d in [-2047,2047], exact integer bucket thresholds.
__global__ void bias_table_kernel(const float* __restrict__ rel,
                                  float* __restrict__ bias_val) {
    int idx = blockIdx.x * 256 + threadIdx.x;
    if (idx >= NH * 4095) return;
    int h = idx / 4095;
    int dd = idx - h * 4095;
    int d = dd - 2047;
    int a = d < 0 ? -d : d;
    int bucket;
    if (a == 0) bucket = 0;
    else if (a < 8) bucket = 16 + a;
    else {
        int k = (a >= 14) + (a >= 23) + (a >= 39) + (a >= 64) +
                (a >= 108) + (a >= 182) + (a >= 305);
        bucket = 24 + k;                     // 16 + min(15, 8+k), k<=7
    }
    bias_val[h * 4095 + dd] = rel[bucket * NH + h];
}

// ---------------------------------------------------------------- projections
// C[M=4096, N=1024] = A[4096,1024] @ W[1024,1024] (+bias)*outscale
// AMODE 0: A fp32   AMODE 1: A bf16
// OMODE 0: bf16 natural; OMODE 1: bf16 transposed per-head [b][h][d][s]; OMODE 2: fp32
template<int AMODE, int OMODE>
__global__ __launch_bounds__(256) void proj_gemm(const void* __restrict__ Ain,
        const float* __restrict__ W, const float* __restrict__ bias,
        void* __restrict__ Out, float outscale) {
    constexpr int KP = 40;                   // LDS pitch (bf16 elems), 80B rows
    __shared__ unsigned short la[128 * KP];
    __shared__ unsigned short lb[128 * KP];  // stores W transposed: lb[n][k]
    const int tid = threadIdx.x;
    const int bx = blockIdx.x & 7, by = blockIdx.x >> 3;
    const int m0 = by * 128, n0 = bx * 128;
    const int lane = tid & 63, wid = tid >> 6;
    const int wm0 = (wid >> 1) * 64, wn0 = (wid & 1) * 64;
    const int l15 = lane & 15, l4 = lane >> 4;
    f32x4 acc[4][4] = {};

    for (int kt = 0; kt < 32; ++kt) {
        const int k0 = kt * 32;
        // stage A tile [128][32] -> la
        if (AMODE == 0) {
            const float* A = (const float*)Ain;
#pragma unroll
            for (int i = 0; i < 4; ++i) {
                int idx = tid + i * 256;
                int row = idx >> 3, c4 = (idx & 7) * 4;
                float4 v = *(const float4*)(A + (size_t)(m0 + row) * DM + k0 + c4);
                ushort4 u; u.x = f2b(v.x); u.y = f2b(v.y); u.z = f2b(v.z); u.w = f2b(v.w);
                *(ushort4*)&la[row * KP + c4] = u;
            }
        } else {
            const unsigned short* A = (const unsigned short*)Ain;
#pragma unroll
            for (int i = 0; i < 2; ++i) {
                int idx = tid + i * 256;
                int row = idx >> 2, c8 = (idx & 3) * 8;
                int4 v = *(const int4*)(A + (size_t)(m0 + row) * DM + k0 + c8);
                *(int4*)&la[row * KP + c8] = v;
            }
        }
        // stage B tile: W[k0..k0+31][n0..n0+127] transposed -> lb[n][k]
#pragma unroll
        for (int i = 0; i < 4; ++i) {
            int idx = tid + i * 256;
            int n = idx & 127, k4 = (idx >> 7) * 4;
            const float* wp = W + (size_t)(k0 + k4) * DM + n0 + n;
            ushort4 u;
            u.x = f2b(wp[0 * DM]); u.y = f2b(wp[1 * DM]);
            u.z = f2b(wp[2 * DM]); u.w = f2b(wp[3 * DM]);
            *(ushort4*)&lb[n * KP + k4] = u;
        }
        __syncthreads();
        bf16x8 af[4], bfv[4];
#pragma unroll
        for (int m = 0; m < 4; ++m)
            af[m] = load_bf8(&la[(wm0 + m * 16 + l15) * KP + l4 * 8]);
#pragma unroll
        for (int n = 0; n < 4; ++n)
            bfv[n] = load_bf8(&lb[(wn0 + n * 16 + l15) * KP + l4 * 8]);
#pragma unroll
        for (int m = 0; m < 4; ++m)
#pragma unroll
            for (int n = 0; n < 4; ++n)
                acc[m][n] = MFMA16(af[m], bfv[n], acc[m][n]);
        __syncthreads();
    }

    float bv[4];
#pragma unroll
    for (int n = 0; n < 4; ++n) bv[n] = bias[n0 + wn0 + n * 16 + l15];
#pragma unroll
    for (int m = 0; m < 4; ++m) {
#pragma unroll
        for (int n = 0; n < 4; ++n) {
            int gcol = n0 + wn0 + n * 16 + l15;
#pragma unroll
            for (int r = 0; r < 4; ++r) {
                int grow = m0 + wm0 + m * 16 + l4 * 4 + r;
                float val = (acc[m][n][r] + bv[n]) * outscale;
                if (OMODE == 0) {
                    ((unsigned short*)Out)[(size_t)grow * DM + gcol] = f2b(val);
                } else if (OMODE == 1) {
                    int b = grow >> 11, s = grow & 2047;
                    int hh = gcol >> 6, dl = gcol & 63;
                    ((unsigned short*)Out)[(((size_t)(b * NH + hh) * DK + dl) << 11) + s] = f2b(val);
                } else {
                    ((float*)Out)[(size_t)grow * DM + gcol] = val;
                }
            }
        }
    }
}

// ---------------------------------------------------------------- attention
// Two-pass online softmax. Block = (b, h, 64 q-rows); each of 4 waves owns 16
// q-rows, runs barrier-free after the bias stage. Pass 1: streaming QK^T+bias
// -> running (max, sum). Pass 2: recompute scores, write normalized weights
// (via per-wave LDS tile for coalescing + P-fragment transpose), PV MFMA.
__global__ __launch_bounds__(256) void attn2_kernel(
        const unsigned short* __restrict__ Qp, const unsigned short* __restrict__ Kp,
        const unsigned short* __restrict__ Vt, const float* __restrict__ bias_val,
        float* __restrict__ attn_out, unsigned short* __restrict__ ctx) {
    __shared__ float bias_lds[2112];
    __shared__ float wtile[4][16 * 36];      // per-wave 16x32 fp32, pitch 36
    const int tid = threadIdx.x;
    const int lane = tid & 63, wid = tid >> 6;
    const int l15 = lane & 15, l4 = lane >> 4;
    const int bid = (blockIdx.x & 7) * 128 + (blockIdx.x >> 3);  // XCD swizzle
    const int qb = bid & 31;
    const int h = (bid >> 5) & 15;
    const int b = bid >> 9;
    const int q0 = qb * 64;
    const int qw = q0 + wid * 16;

    {   // bias slice for rows q0..q0+63: bias_lds[c - qlocal + 63]
        const float* bp = bias_val + h * 4095 + (2047 - (q0 + 63));
        for (int i = tid; i < 2111; i += 256) bias_lds[i] = bp[i];
    }
    __syncthreads();

    const unsigned short* qbase = Qp + (size_t)(b * SEQ + qw + l15) * DM + h * DK;
    bf16x8 qa0 = load_bf8(qbase + l4 * 8);
    bf16x8 qa1 = load_bf8(qbase + 32 + l4 * 8);

    const unsigned short* kbase = Kp + (size_t)b * SEQ * DM + h * DK;
    const int bbase = 63 - wid * 16 - l4 * 4;   // bias idx = c + bbase - r

    float m[4], l[4];
#pragma unroll
    for (int r = 0; r < 4; ++r) { m[r] = -3e38f; l[r] = 0.f; }

    // ---- pass 1: running max/sum
    for (int c0 = 0; c0 < SEQ; c0 += 32) {
        const unsigned short* kp = kbase + (size_t)(c0 + l15) * DM;
        bf16x8 k00 = load_bf8(kp + l4 * 8);
        bf16x8 k01 = load_bf8(kp + 32 + l4 * 8);
        bf16x8 k10 = load_bf8(kp + 16 * DM + l4 * 8);
        bf16x8 k11 = load_bf8(kp + 16 * DM + 32 + l4 * 8);
        f32x4 a0 = {}, a1 = {};
        a0 = MFMA16(qa0, k00, a0); a0 = MFMA16(qa1, k01, a0);
        a1 = MFMA16(qa0, k10, a1); a1 = MFMA16(qa1, k11, a1);
#pragma unroll
        for (int r = 0; r < 4; ++r) {
            float s0 = a0[r] + bias_lds[c0 + l15 + bbase - r];
            float s1 = a1[r] + bias_lds[c0 + 16 + l15 + bbase - r];
            float cm = fmaxf(s0, s1);
            if (cm > m[r]) { l[r] *= __expf(m[r] - cm); m[r] = cm; }
            l[r] += __expf(s0 - m[r]) + __expf(s1 - m[r]);
        }
    }
    // merge across the 16 lanes sharing the same 4 rows
#pragma unroll
    for (int off = 1; off < 16; off <<= 1) {
#pragma unroll
        for (int r = 0; r < 4; ++r) {
            float om = __shfl_xor(m[r], off);
            float ol = __shfl_xor(l[r], off);
            float M = fmaxf(m[r], om);
            l[r] = l[r] * __expf(m[r] - M) + ol * __expf(om - M);
            m[r] = M;
        }
    }
    float invl[4];
#pragma unroll
    for (int r = 0; r < 4; ++r) invl[r] = 1.0f / l[r];

    // ---- pass 2: normalized weights out + PV
    float* wt = wtile[wid];
    float* abase = attn_out + ((size_t)((b * NH + h) * SEQ + qw)) * SEQ;
    const unsigned short* vbase = Vt + (((size_t)(b * NH + h) * DK) << 11);
    f32x4 cacc[4] = {};

    bf16x8 k00, k01, k10, k11;
    {
        const unsigned short* kp = kbase + (size_t)l15 * DM;
        k00 = load_bf8(kp + l4 * 8);
        k01 = load_bf8(kp + 32 + l4 * 8);
        k10 = load_bf8(kp + 16 * DM + l4 * 8);
        k11 = load_bf8(kp + 16 * DM + 32 + l4 * 8);
    }
    for (int c0 = 0; c0 < SEQ; c0 += 32) {
        f32x4 a0 = {}, a1 = {};
        a0 = MFMA16(qa0, k00, a0); a0 = MFMA16(qa1, k01, a0);
        a1 = MFMA16(qa0, k10, a1); a1 = MFMA16(qa1, k11, a1);
        // prefetch next K chunk + this chunk's V (independent of LDS fences)
        const int cn = (c0 + 32) & (SEQ - 1);
        const unsigned short* kp = kbase + (size_t)(cn + l15) * DM;
        k00 = load_bf8(kp + l4 * 8);
        k01 = load_bf8(kp + 32 + l4 * 8);
        k10 = load_bf8(kp + 16 * DM + l4 * 8);
        k11 = load_bf8(kp + 16 * DM + 32 + l4 * 8);
        bf16x8 vv0 = load_bf8(vbase + ((size_t)(0 * 16 + l15) << 11) + c0 + l4 * 8);
        bf16x8 vv1 = load_bf8(vbase + ((size_t)(1 * 16 + l15) << 11) + c0 + l4 * 8);
        bf16x8 vv2 = load_bf8(vbase + ((size_t)(2 * 16 + l15) << 11) + c0 + l4 * 8);
        bf16x8 vv3 = load_bf8(vbase + ((size_t)(3 * 16 + l15) << 11) + c0 + l4 * 8);
#pragma unroll
        for (int r = 0; r < 4; ++r) {
            int row = l4 * 4 + r;
            float w0 = __expf(a0[r] + bias_lds[c0 + l15 + bbase - r] - m[r]) * invl[r];
            float w1 = __expf(a1[r] + bias_lds[c0 + 16 + l15 + bbase - r] - m[r]) * invl[r];
            wt[row * 36 + l15] = w0;
            wt[row * 36 + 16 + l15] = w1;
        }
        // wave-private tile: order write->read with explicit fence (rule #18)
        asm volatile("s_waitcnt lgkmcnt(0)" ::: "memory");
        __builtin_amdgcn_sched_barrier(0);
        {   // coalesced fp32 weight write: 4 lanes x 32B = 128B per row
            int row = lane >> 2, cg = (lane & 3) * 8;
            float4 v0 = *(const float4*)&wt[row * 36 + cg];
            float4 v1 = *(const float4*)&wt[row * 36 + cg + 4];
            float* gp = abase + (size_t)row * SEQ + c0 + cg;
            *(float4*)gp = v0;
            *(float4*)(gp + 4) = v1;
        }
        // P fragment (A-layout: row=l15, k=l4*8+j) from the same tile
        float4 pA = *(const float4*)&wt[l15 * 36 + l4 * 8];
        float4 pB = *(const float4*)&wt[l15 * 36 + l4 * 8 + 4];
        short8 ps;
        ps[0] = (short)f2b(pA.x); ps[1] = (short)f2b(pA.y);
        ps[2] = (short)f2b(pA.z); ps[3] = (short)f2b(pA.w);
        ps[4] = (short)f2b(pB.x); ps[5] = (short)f2b(pB.y);
        ps[6] = (short)f2b(pB.z); ps[7] = (short)f2b(pB.w);
        bf16x8 pf = __builtin_bit_cast(bf16x8, ps);
        cacc[0] = MFMA16(pf, vv0, cacc[0]);
        cacc[1] = MFMA16(pf, vv1, cacc[1]);
        cacc[2] = MFMA16(pf, vv2, cacc[2]);
        cacc[3] = MFMA16(pf, vv3, cacc[3]);
        // WAR fence: reads of this chunk done before next chunk's writes
        asm volatile("s_waitcnt lgkmcnt(0)" ::: "memory");
        __builtin_amdgcn_sched_barrier(0);
    }
#pragma unroll
    for (int d0 = 0; d0 < 4; ++d0)
#pragma unroll
        for (int r = 0; r < 4; ++r)
            ctx[(size_t)(b * SEQ + qw + l4 * 4 + r) * DM + h * DK + d0 * 16 + l15] =
                f2b(cacc[d0][r]);
}

// ---------------------------------------------------------------- pb writer
__global__ __launch_bounds__(256) void pb_kernel(const float* __restrict__ bias_val,
                                                 float* __restrict__ pb) {
    unsigned int t4 = blockIdx.x * 256u + threadIdx.x;
    int j = (t4 & 511) * 4;
    int i = (t4 >> 9) & 2047;
    int h = t4 >> 20;
    const float* bp = bias_val + h * 4095 + (j - i + 2047);
    float4 v; v.x = bp[0]; v.y = bp[1]; v.z = bp[2]; v.w = bp[3];
    size_t off = ((size_t)(h * SEQ + i) << 11) + j;
    *(float4*)(pb + off) = v;
    *(float4*)(pb + off + (size_t)NH * SEQ * SEQ) = v;
}

// ---------------------------------------------------------------- launcher
extern "C" void kernel_launch(void* const* d_in, const int* in_sizes, int n_in,
                              void* d_out, int out_size, void* d_ws, size_t ws_size,
                              hipStream_t stream) {
    const float* query = (const float*)d_in[0];
    const float* key   = (const float*)d_in[1];
    const float* value = (const float*)d_in[2];
    const float* Wq = (const float*)d_in[3];
    const float* bq = (const float*)d_in[4];
    const float* Wk = (const float*)d_in[5];
    const float* bk = (const float*)d_in[6];
    const float* Wv = (const float*)d_in[7];
    const float* bv = (const float*)d_in[8];
    const float* Wo = (const float*)d_in[9];
    const float* bo = (const float*)d_in[10];
    const float* rel = (const float*)d_in[11];

    float* out = (float*)d_out;
    float* attn_out = out + (size_t)BN * SEQ * DM;                 // 4,194,304
    float* pb_out = attn_out + (size_t)BN * NH * SEQ * SEQ;        // +134,217,728

    char* ws = (char*)d_ws;
    float* bias_val = (float*)ws;                                  // 256KB slot
    unsigned short* Qp = (unsigned short*)(ws + 262144);
    unsigned short* Kp = Qp + (size_t)BN * SEQ * DM;
    unsigned short* Vt = Kp + (size_t)BN * SEQ * DM;
    unsigned short* ctx = Vt + (size_t)BN * SEQ * DM;

    bias_table_kernel<<<256, 256, 0, stream>>>(rel, bias_val);
    proj_gemm<0, 0><<<256, 256, 0, stream>>>(query, Wq, bq, Qp, 0.125f);
    proj_gemm<0, 0><<<256, 256, 0, stream>>>(key, Wk, bk, Kp, 1.0f);
    proj_gemm<0, 1><<<256, 256, 0, stream>>>(value, Wv, bv, Vt, 1.0f);
    attn2_kernel<<<BN * NH * (SEQ / 64), 256, 0, stream>>>(Qp, Kp, Vt, bias_val, attn_out, ctx);
    proj_gemm<1, 2><<<256, 256, 0, stream>>>(ctx, Wo, bo, out, 1.0f);
    pb_kernel<<<65536, 256, 0, stream>>>(bias_val, pb_out);
}

// Round 3
// 601.007 us; speedup vs baseline: 1.5927x; 1.1813x over previous
//
#include <hip/hip_runtime.h>
#include <hip/hip_bf16.h>

#define BN 2
#define SEQ 2048
#define DM 1024
#define NH 16
#define DK 64

using f32x4  = __attribute__((ext_vector_type(4))) float;
using bf16x8 = __attribute__((ext_vector_type(8))) __bf16;
using short8 = __attribute__((ext_vector_type(8))) short;

static_assert(sizeof(bf16x8) == 16, "bf16x8 must be 16B");

#define MFMA16(a, b, c) __builtin_amdgcn_mfma_f32_16x16x32_bf16(a, b, c, 0, 0, 0)

__device__ __forceinline__ unsigned short f2b(float f) {
    __hip_bfloat16 h = __float2bfloat16(f);
    return __builtin_bit_cast(unsigned short, h);
}

__device__ __forceinline__ bf16x8 load_bf8(const unsigned short* p) {
    short8 s = *reinterpret_cast<const short8*>(p);
    return __builtin_bit_cast(bf16x8, s);
}

// ---------------------------------------------------------------- bias table
__global__ void bias_table_kernel(const float* __restrict__ rel,
                                  float* __restrict__ bias_val) {
    int idx = blockIdx.x * 256 + threadIdx.x;
    if (idx >= NH * 4095) return;
    int h = idx / 4095;
    int dd = idx - h * 4095;
    int d = dd - 2047;
    int a = d < 0 ? -d : d;
    int bucket;
    if (a == 0) bucket = 0;
    else if (a < 8) bucket = 16 + a;
    else {
        int k = (a >= 14) + (a >= 23) + (a >= 39) + (a >= 64) +
                (a >= 108) + (a >= 182) + (a >= 305);
        bucket = 24 + k;
    }
    bias_val[h * 4095 + dd] = rel[bucket * NH + h];
}

// ---------------------------------------------------------------- weight prep
// W[k][n] fp32 -> Wt[n][k] bf16, 64x64 tiles via LDS. z selects matrix.
__global__ __launch_bounds__(256) void wtrans_kernel(
        const float* __restrict__ W0, const float* __restrict__ W1,
        const float* __restrict__ W2, const float* __restrict__ W3,
        unsigned short* __restrict__ T0, unsigned short* __restrict__ T1,
        unsigned short* __restrict__ T2, unsigned short* __restrict__ T3) {
    constexpr int P = 68;
    __shared__ unsigned short lt[64 * P];
    const int mz = blockIdx.z;
    const float* W = mz == 0 ? W0 : mz == 1 ? W1 : mz == 2 ? W2 : W3;
    unsigned short* T = mz == 0 ? T0 : mz == 1 ? T1 : mz == 2 ? T2 : T3;
    const int k0 = blockIdx.x * 64, n0 = blockIdx.y * 64;
    const int tid = threadIdx.x;
#pragma unroll
    for (int p = 0; p < 4; ++p) {
        int r = p * 16 + (tid >> 4);      // k
        int c = (tid & 15) * 4;           // n
        float4 vv = *(const float4*)&W[(size_t)(k0 + r) * DM + n0 + c];
#pragma unroll
        for (int j = 0; j < 4; ++j) {
            int n = c + j;
            float x = j == 0 ? vv.x : j == 1 ? vv.y : j == 2 ? vv.z : vv.w;
            lt[n * P + (r ^ ((n & 7) << 3))] = f2b(x);
        }
    }
    __syncthreads();
#pragma unroll
    for (int p = 0; p < 2; ++p) {
        int rn = p * 32 + (tid >> 3);     // n
        int ck = (tid & 7) * 8;           // k
        int ckx = ck ^ ((rn & 7) << 3);
        ushort4 a0 = *(ushort4*)&lt[rn * P + ckx];
        ushort4 a1 = *(ushort4*)&lt[rn * P + ckx + 4];
        *(ushort4*)&T[(size_t)(n0 + rn) * DM + k0 + ck] = a0;
        *(ushort4*)&T[(size_t)(n0 + rn) * DM + k0 + ck + 4] = a1;
    }
}

// ---------------------------------------------------------------- fused QKV GEMM
// z=0: Q natural bf16 *0.125; z=1: K head-major Kh[b][h][s][d]; z=2: V -> Vt[b][h][d][s]
__global__ __launch_bounds__(256) void qkv_gemm(
        const float* __restrict__ Aq, const float* __restrict__ Ak, const float* __restrict__ Av,
        const unsigned short* __restrict__ Wtq, const unsigned short* __restrict__ Wtk,
        const unsigned short* __restrict__ Wtv,
        const float* __restrict__ bq, const float* __restrict__ bk, const float* __restrict__ bv,
        unsigned short* __restrict__ Qp, unsigned short* __restrict__ Kh,
        unsigned short* __restrict__ Vt) {
    constexpr int KP = 40;
    __shared__ unsigned short la[128 * KP];
    __shared__ unsigned short lb[128 * KP];
    const int mat = blockIdx.z;
    const float* A = mat == 0 ? Aq : mat == 1 ? Ak : Av;
    const unsigned short* Wt = mat == 0 ? Wtq : mat == 1 ? Wtk : Wtv;
    const float* bias = mat == 0 ? bq : mat == 1 ? bk : bv;
    const float outscale = mat == 0 ? 0.125f : 1.0f;
    const int tid = threadIdx.x;
    const int m0 = blockIdx.y * 128, n0 = blockIdx.x * 128;
    const int lane = tid & 63, wid = tid >> 6;
    const int wm0 = (wid >> 1) * 64, wn0 = (wid & 1) * 64;
    const int l15 = lane & 15, l4 = lane >> 4;
    f32x4 acc[4][4] = {};

    for (int kt = 0; kt < 32; ++kt) {
        const int k0 = kt * 32;
#pragma unroll
        for (int i = 0; i < 4; ++i) {
            int idx = tid + i * 256;
            int row = idx >> 3, c4 = (idx & 7) * 4;
            float4 v = *(const float4*)(A + (size_t)(m0 + row) * DM + k0 + c4);
            ushort4 u; u.x = f2b(v.x); u.y = f2b(v.y); u.z = f2b(v.z); u.w = f2b(v.w);
            *(ushort4*)&la[row * KP + c4] = u;
        }
#pragma unroll
        for (int i = 0; i < 2; ++i) {
            int idx = tid + i * 256;
            int row = idx >> 2, c8 = (idx & 3) * 8;
            *(int4*)&lb[row * KP + c8] =
                *(const int4*)&Wt[(size_t)(n0 + row) * DM + k0 + c8];
        }
        __syncthreads();
        bf16x8 af[4], bfv[4];
#pragma unroll
        for (int m = 0; m < 4; ++m)
            af[m] = load_bf8(&la[(wm0 + m * 16 + l15) * KP + l4 * 8]);
#pragma unroll
        for (int n = 0; n < 4; ++n)
            bfv[n] = load_bf8(&lb[(wn0 + n * 16 + l15) * KP + l4 * 8]);
#pragma unroll
        for (int m = 0; m < 4; ++m)
#pragma unroll
            for (int n = 0; n < 4; ++n)
                acc[m][n] = MFMA16(af[m], bfv[n], acc[m][n]);
        __syncthreads();
    }

    float bv4[4];
#pragma unroll
    for (int n = 0; n < 4; ++n) bv4[n] = bias[n0 + wn0 + n * 16 + l15];
#pragma unroll
    for (int m = 0; m < 4; ++m) {
#pragma unroll
        for (int n = 0; n < 4; ++n) {
            int gcol = n0 + wn0 + n * 16 + l15;
#pragma unroll
            for (int r = 0; r < 4; ++r) {
                int grow = m0 + wm0 + m * 16 + l4 * 4 + r;
                float val = (acc[m][n][r] + bv4[n]) * outscale;
                unsigned short ob = f2b(val);
                int b = grow >> 11, s = grow & 2047;
                int hh = gcol >> 6, dl = gcol & 63;
                if (mat == 0) {
                    Qp[(size_t)grow * DM + gcol] = ob;
                } else if (mat == 1) {
                    Kh[(((size_t)(b * NH + hh) * SEQ + s) << 6) + dl] = ob;
                } else {
                    Vt[(((size_t)(b * NH + hh) * DK + dl) << 11) + s] = ob;
                }
            }
        }
    }
}

// ---------------------------------------------------------------- O projection
// 64x128 tile, 512 blocks (2/CU). A = ctx bf16, out fp32.
__global__ __launch_bounds__(256) void o_gemm(
        const unsigned short* __restrict__ Actx, const unsigned short* __restrict__ Wto,
        const float* __restrict__ bo, float* __restrict__ out) {
    constexpr int KP = 40;
    __shared__ unsigned short la[64 * KP];
    __shared__ unsigned short lb[128 * KP];
    const int tid = threadIdx.x;
    const int m0 = blockIdx.y * 64, n0 = blockIdx.x * 128;
    const int lane = tid & 63, wid = tid >> 6;
    const int wm0 = (wid >> 1) * 32, wn0 = (wid & 1) * 64;
    const int l15 = lane & 15, l4 = lane >> 4;
    f32x4 acc[2][4] = {};

    for (int kt = 0; kt < 32; ++kt) {
        const int k0 = kt * 32;
        {
            int row = tid >> 2, c8 = (tid & 3) * 8;
            *(int4*)&la[row * KP + c8] =
                *(const int4*)&Actx[(size_t)(m0 + row) * DM + k0 + c8];
        }
#pragma unroll
        for (int i = 0; i < 2; ++i) {
            int idx = tid + i * 256;
            int row = idx >> 2, c8 = (idx & 3) * 8;
            *(int4*)&lb[row * KP + c8] =
                *(const int4*)&Wto[(size_t)(n0 + row) * DM + k0 + c8];
        }
        __syncthreads();
        bf16x8 af[2], bfv[4];
#pragma unroll
        for (int m = 0; m < 2; ++m)
            af[m] = load_bf8(&la[(wm0 + m * 16 + l15) * KP + l4 * 8]);
#pragma unroll
        for (int n = 0; n < 4; ++n)
            bfv[n] = load_bf8(&lb[(wn0 + n * 16 + l15) * KP + l4 * 8]);
#pragma unroll
        for (int m = 0; m < 2; ++m)
#pragma unroll
            for (int n = 0; n < 4; ++n)
                acc[m][n] = MFMA16(af[m], bfv[n], acc[m][n]);
        __syncthreads();
    }

#pragma unroll
    for (int m = 0; m < 2; ++m)
#pragma unroll
        for (int n = 0; n < 4; ++n) {
            int gcol = n0 + wn0 + n * 16 + l15;
            float bb = bo[gcol];
#pragma unroll
            for (int r = 0; r < 4; ++r) {
                int grow = m0 + wm0 + m * 16 + l4 * 4 + r;
                out[(size_t)grow * DM + gcol] = acc[m][n][r] + bb;
            }
        }
}

// ---------------------------------------------------------------- attention
// Two-pass online softmax; block = (b,h,64 q-rows), 4 waves x 16 rows.
// K head-major (coalesced), pb slice fused into pass 2.
__global__ __launch_bounds__(256) void attn3_kernel(
        const unsigned short* __restrict__ Qp, const unsigned short* __restrict__ Kh,
        const unsigned short* __restrict__ Vt, const float* __restrict__ bias_val,
        float* __restrict__ attn_out, float* __restrict__ pb_out,
        unsigned short* __restrict__ ctx) {
    __shared__ float bias_lds[2112];
    __shared__ float wtile[4][16 * 36];
    const int tid = threadIdx.x;
    const int lane = tid & 63, wid = tid >> 6;
    const int l15 = lane & 15, l4 = lane >> 4;
    const int bid = (blockIdx.x & 7) * 128 + (blockIdx.x >> 3);  // XCD swizzle
    const int qb = bid & 31;
    const int h = (bid >> 5) & 15;
    const int b = bid >> 9;
    const int q0 = qb * 64;
    const int qw = q0 + wid * 16;

    {
        const float* bp = bias_val + h * 4095 + (2047 - (q0 + 63));
        for (int i = tid; i < 2111; i += 256) bias_lds[i] = bp[i];
    }
    __syncthreads();

    const unsigned short* qbase = Qp + (size_t)(b * SEQ + qw + l15) * DM + h * DK;
    bf16x8 qa0 = load_bf8(qbase + l4 * 8);
    bf16x8 qa1 = load_bf8(qbase + 32 + l4 * 8);

    const unsigned short* kbase = Kh + (((size_t)(b * NH + h) * SEQ) << 6);
    const int bbase = 63 - wid * 16 - l4 * 4;

    float m[4], l[4];
#pragma unroll
    for (int r = 0; r < 4; ++r) { m[r] = -3e38f; l[r] = 0.f; }

    // ---- pass 1
    for (int c0 = 0; c0 < SEQ; c0 += 32) {
        const unsigned short* kp = kbase + ((size_t)(c0 + l15) << 6);
        bf16x8 k00 = load_bf8(kp + l4 * 8);
        bf16x8 k01 = load_bf8(kp + 32 + l4 * 8);
        bf16x8 k10 = load_bf8(kp + (16 << 6) + l4 * 8);
        bf16x8 k11 = load_bf8(kp + (16 << 6) + 32 + l4 * 8);
        f32x4 a0 = {}, a1 = {};
        a0 = MFMA16(qa0, k00, a0); a0 = MFMA16(qa1, k01, a0);
        a1 = MFMA16(qa0, k10, a1); a1 = MFMA16(qa1, k11, a1);
#pragma unroll
        for (int r = 0; r < 4; ++r) {
            float s0 = a0[r] + bias_lds[c0 + l15 + bbase - r];
            float s1 = a1[r] + bias_lds[c0 + 16 + l15 + bbase - r];
            float cm = fmaxf(s0, s1);
            if (cm > m[r]) { l[r] *= __expf(m[r] - cm); m[r] = cm; }
            l[r] += __expf(s0 - m[r]) + __expf(s1 - m[r]);
        }
    }
#pragma unroll
    for (int off = 1; off < 16; off <<= 1) {
#pragma unroll
        for (int r = 0; r < 4; ++r) {
            float om = __shfl_xor(m[r], off);
            float ol = __shfl_xor(l[r], off);
            float M = fmaxf(m[r], om);
            l[r] = l[r] * __expf(m[r] - M) + ol * __expf(om - M);
            m[r] = M;
        }
    }
    float invl[4];
#pragma unroll
    for (int r = 0; r < 4; ++r) invl[r] = 1.0f / l[r];

    // ---- pass 2
    float* wt = wtile[wid];
    float* abase = attn_out + ((size_t)((b * NH + h) * SEQ + qw)) * SEQ;
    float* pbase = pb_out + ((size_t)((b * NH + h) * SEQ + qw)) * SEQ;
    const unsigned short* vbase = Vt + (((size_t)(b * NH + h) * DK) << 11);
    f32x4 cacc[4] = {};

    bf16x8 k00, k01, k10, k11;
    {
        const unsigned short* kp = kbase + ((size_t)l15 << 6);
        k00 = load_bf8(kp + l4 * 8);
        k01 = load_bf8(kp + 32 + l4 * 8);
        k10 = load_bf8(kp + (16 << 6) + l4 * 8);
        k11 = load_bf8(kp + (16 << 6) + 32 + l4 * 8);
    }
    const int srow = lane >> 2, scg = (lane & 3) * 8;   // store decomposition
    for (int c0 = 0; c0 < SEQ; c0 += 32) {
        f32x4 a0 = {}, a1 = {};
        a0 = MFMA16(qa0, k00, a0); a0 = MFMA16(qa1, k01, a0);
        a1 = MFMA16(qa0, k10, a1); a1 = MFMA16(qa1, k11, a1);
        const int cn = (c0 + 32) & (SEQ - 1);
        const unsigned short* kp = kbase + ((size_t)(cn + l15) << 6);
        k00 = load_bf8(kp + l4 * 8);
        k01 = load_bf8(kp + 32 + l4 * 8);
        k10 = load_bf8(kp + (16 << 6) + l4 * 8);
        k11 = load_bf8(kp + (16 << 6) + 32 + l4 * 8);
        bf16x8 vv0 = load_bf8(vbase + ((size_t)(0 * 16 + l15) << 11) + c0 + l4 * 8);
        bf16x8 vv1 = load_bf8(vbase + ((size_t)(1 * 16 + l15) << 11) + c0 + l4 * 8);
        bf16x8 vv2 = load_bf8(vbase + ((size_t)(2 * 16 + l15) << 11) + c0 + l4 * 8);
        bf16x8 vv3 = load_bf8(vbase + ((size_t)(3 * 16 + l15) << 11) + c0 + l4 * 8);
#pragma unroll
        for (int r = 0; r < 4; ++r) {
            int row = l4 * 4 + r;
            float w0 = __expf(a0[r] + bias_lds[c0 + l15 + bbase - r] - m[r]) * invl[r];
            float w1 = __expf(a1[r] + bias_lds[c0 + 16 + l15 + bbase - r] - m[r]) * invl[r];
            wt[row * 36 + l15] = w0;
            wt[row * 36 + 16 + l15] = w1;
        }
        asm volatile("s_waitcnt lgkmcnt(0)" ::: "memory");
        __builtin_amdgcn_sched_barrier(0);
        {   // attn weights: 16 rows x 128B segments
            float4 v0 = *(const float4*)&wt[srow * 36 + scg];
            float4 v1 = *(const float4*)&wt[srow * 36 + scg + 4];
            float* gp = abase + (size_t)srow * SEQ + c0 + scg;
            *(float4*)gp = v0;
            *(float4*)(gp + 4) = v1;
        }
        {   // fused pb slice: same decomposition, values from bias_lds diagonals
            const int ib = c0 + scg + bbase + l4 * 4 - srow;  // bias_lds idx base
            float4 p0, p1;
            p0.x = bias_lds[ib + 0]; p0.y = bias_lds[ib + 1];
            p0.z = bias_lds[ib + 2]; p0.w = bias_lds[ib + 3];
            p1.x = bias_lds[ib + 4]; p1.y = bias_lds[ib + 5];
            p1.z = bias_lds[ib + 6]; p1.w = bias_lds[ib + 7];
            float* gp = pbase + (size_t)srow * SEQ + c0 + scg;
            *(float4*)gp = p0;
            *(float4*)(gp + 4) = p1;
        }
        float4 pA = *(const float4*)&wt[l15 * 36 + l4 * 8];
        float4 pB = *(const float4*)&wt[l15 * 36 + l4 * 8 + 4];
        short8 ps;
        ps[0] = (short)f2b(pA.x); ps[1] = (short)f2b(pA.y);
        ps[2] = (short)f2b(pA.z); ps[3] = (short)f2b(pA.w);
        ps[4] = (short)f2b(pB.x); ps[5] = (short)f2b(pB.y);
        ps[6] = (short)f2b(pB.z); ps[7] = (short)f2b(pB.w);
        bf16x8 pf = __builtin_bit_cast(bf16x8, ps);
        cacc[0] = MFMA16(pf, vv0, cacc[0]);
        cacc[1] = MFMA16(pf, vv1, cacc[1]);
        cacc[2] = MFMA16(pf, vv2, cacc[2]);
        cacc[3] = MFMA16(pf, vv3, cacc[3]);
        asm volatile("s_waitcnt lgkmcnt(0)" ::: "memory");
        __builtin_amdgcn_sched_barrier(0);
    }
#pragma unroll
    for (int d0 = 0; d0 < 4; ++d0)
#pragma unroll
        for (int r = 0; r < 4; ++r)
            ctx[(size_t)(b * SEQ + qw + l4 * 4 + r) * DM + h * DK + d0 * 16 + l15] =
                f2b(cacc[d0][r]);
}

// ---------------------------------------------------------------- launcher
extern "C" void kernel_launch(void* const* d_in, const int* in_sizes, int n_in,
                              void* d_out, int out_size, void* d_ws, size_t ws_size,
                              hipStream_t stream) {
    const float* query = (const float*)d_in[0];
    const float* key   = (const float*)d_in[1];
    const float* value = (const float*)d_in[2];
    const float* Wq = (const float*)d_in[3];
    const float* bq = (const float*)d_in[4];
    const float* Wk = (const float*)d_in[5];
    const float* bk = (const float*)d_in[6];
    const float* Wv = (const float*)d_in[7];
    const float* bv = (const float*)d_in[8];
    const float* Wo = (const float*)d_in[9];
    const float* bo = (const float*)d_in[10];
    const float* rel = (const float*)d_in[11];

    float* out = (float*)d_out;
    float* attn_out = out + (size_t)BN * SEQ * DM;
    float* pb_out = attn_out + (size_t)BN * NH * SEQ * SEQ;

    char* ws = (char*)d_ws;
    float* bias_val = (float*)ws;                                   // 256KB slot
    unsigned short* Qp  = (unsigned short*)(ws + 262144);
    unsigned short* Kh  = Qp + (size_t)BN * SEQ * DM;
    unsigned short* Vt  = Kh + (size_t)BN * SEQ * DM;
    unsigned short* ctx = Vt + (size_t)BN * SEQ * DM;
    unsigned short* Wtq = ctx + (size_t)BN * SEQ * DM;
    unsigned short* Wtk = Wtq + (size_t)DM * DM;
    unsigned short* Wtv = Wtk + (size_t)DM * DM;
    unsigned short* Wto = Wtv + (size_t)DM * DM;

    bias_table_kernel<<<256, 256, 0, stream>>>(rel, bias_val);
    wtrans_kernel<<<dim3(16, 16, 4), 256, 0, stream>>>(Wq, Wk, Wv, Wo, Wtq, Wtk, Wtv, Wto);
    qkv_gemm<<<dim3(8, 32, 3), 256, 0, stream>>>(query, key, value, Wtq, Wtk, Wtv,
                                                 bq, bk, bv, Qp, Kh, Vt);
    attn3_kernel<<<BN * NH * (SEQ / 64), 256, 0, stream>>>(Qp, Kh, Vt, bias_val,
                                                           attn_out, pb_out, ctx);
    o_gemm<<<dim3(8, 64), 256, 0, stream>>>(ctx, Wto, bo, out);
}